// Round 12
// baseline (283.705 us; speedup 1.0000x reference)
//
#include <hip/hip_runtime.h>
#include <hip/hip_bf16.h>
#include <math.h>
#include <stdint.h>

#define IN_C 128
#define HID  256
#define OUT_C 2

// bucketing for CSR build: 256 nodes per bucket
#define BSHIFT 8
#define BNODES 256
#define EPB 4096        // edges per k_scatter block (divisible by 4)
#define HISTB 784       // blocks of k_prep that do the histogram
#define PADB 768        // max pad slack per bucket (3 * 256)

typedef __attribute__((ext_vector_type(8))) short short8;
typedef __attribute__((ext_vector_type(4))) float f32x4;
typedef __attribute__((ext_vector_type(2))) float f32x2;

#if defined(__has_builtin)
#if __has_builtin(__builtin_amdgcn_cvt_pk_f32_fp8) && __has_builtin(__builtin_amdgcn_cvt_pk_fp8_f32)
#define HAVE_FP8_CVT 1
#endif
#endif

__device__ __forceinline__ ushort f2bf(float f) {
  uint32_t u = __float_as_uint(f);
  uint32_t r = u + 0x7FFF + ((u >> 16) & 1);   // RNE
  return (ushort)(r >> 16);
}
__device__ __forceinline__ float bf2f(ushort b) {
  return __uint_as_float(((uint32_t)b) << 16);
}

#ifndef HAVE_FP8_CVT
__device__ __forceinline__ uint32_t f2fp8_1(float f) {
  uint32_t u = __float_as_uint(f);
  uint32_t s = (u >> 24) & 0x80;
  float a = fabsf(f);
  if (a >= 448.f) return s | 0x7E;
  if (a < 0.015625f) {
    uint32_t m = (uint32_t)(a * 512.f + 0.5f);
    return s | m;
  }
  uint32_t r = u & 0x7fffffff;
  r += 0x7FFFF + ((r >> 20) & 1);
  uint32_t e = (r >> 23) - 127;
  if ((int)e > 8) return s | 0x7E;
  return s | ((e + 7) << 3) | ((r >> 20) & 7);
}
__device__ __forceinline__ float fp8_2f(uint32_t b) {
  uint32_t s = (b & 0x80) << 24;
  uint32_t e = (b >> 3) & 0xF, m = b & 7;
  if (e == 0) { float f = (float)m * 0.001953125f; return s ? -f : f; }
  return __uint_as_float(s | ((e + 120) << 23) | (m << 20));
}
#endif

__device__ __forceinline__ void acc8f8v(f32x2* s, uint2 v) {
#ifdef HAVE_FP8_CVT
  s[0] += __builtin_amdgcn_cvt_pk_f32_fp8(v.x, false);
  s[1] += __builtin_amdgcn_cvt_pk_f32_fp8(v.x, true);
  s[2] += __builtin_amdgcn_cvt_pk_f32_fp8(v.y, false);
  s[3] += __builtin_amdgcn_cvt_pk_f32_fp8(v.y, true);
#else
  s[0].x += fp8_2f(v.x & 0xff);         s[0].y += fp8_2f((v.x >> 8) & 0xff);
  s[1].x += fp8_2f((v.x >> 16) & 0xff); s[1].y += fp8_2f(v.x >> 24);
  s[2].x += fp8_2f(v.y & 0xff);         s[2].y += fp8_2f((v.y >> 8) & 0xff);
  s[3].x += fp8_2f((v.y >> 16) & 0xff); s[3].y += fp8_2f(v.y >> 24);
#endif
}

// ---------------------------------------------------------------------------
// Fused prep: x -> bf16+fp8, weight casts, root detection, hp zero,
// zero-row init, AND the bucket histogram (int4-batched dst loads).
// ---------------------------------------------------------------------------

__global__ void k_prep(const float* __restrict__ x, ushort* __restrict__ xb,
                       uint32_t* __restrict__ xf8, int n4,
                       const float* __restrict__ Wl, const float* __restrict__ Wr,
                       ushort* __restrict__ Wcat,
                       const float* __restrict__ W0, ushort* __restrict__ W0b,
                       const float* __restrict__ W1, ushort* __restrict__ W1b,
                       const int* __restrict__ batch, int* __restrict__ root, int n,
                       const int* __restrict__ dst, int E, int* __restrict__ bcount,
                       float* __restrict__ hp, int hp4) {
  __shared__ int h[512];
  int t = threadIdx.x;
  int i = blockIdx.x * 256 + t;
  if (i < n4) {
    float4 v = ((const float4*)x)[i];
    ushort4 o = {f2bf(v.x), f2bf(v.y), f2bf(v.z), f2bf(v.w)};
    ((ushort4*)xb)[i] = o;
#ifdef HAVE_FP8_CVT
    int p = __builtin_amdgcn_cvt_pk_fp8_f32(v.x, v.y, 0, false);
    p = __builtin_amdgcn_cvt_pk_fp8_f32(v.z, v.w, p, true);
    xf8[i] = (uint32_t)p;
#else
    xf8[i] = f2fp8_1(v.x) | (f2fp8_1(v.y) << 8) | (f2fp8_1(v.z) << 16) |
             (f2fp8_1(v.w) << 24);
#endif
  }
  if (i < 32) xf8[(size_t)n * 32 + i] = 0;   // zero row (pad target)
  if (i < HID * (2 * IN_C) / 4) {
    int c = i >> 6, c4 = (i & 63) * 4;
    float4 v = (c4 < IN_C) ? *(const float4*)(Wl + (size_t)c * IN_C + c4)
                           : *(const float4*)(Wr + (size_t)c * IN_C + (c4 - IN_C));
    ushort4 o = {f2bf(v.x), f2bf(v.y), f2bf(v.z), f2bf(v.w)};
    *(ushort4*)(Wcat + (size_t)c * (2 * IN_C) + c4) = o;
  }
  if (i < HID * IN_C / 4) {
    float4 v = ((const float4*)W0)[i];
    ushort4 o = {f2bf(v.x), f2bf(v.y), f2bf(v.z), f2bf(v.w)};
    ((ushort4*)W0b)[i] = o;
  }
  if (i < HID * 2 * HID / 4) {
    float4 v = ((const float4*)W1)[i];
    ushort4 o = {f2bf(v.x), f2bf(v.y), f2bf(v.z), f2bf(v.w)};
    ((ushort4*)W1b)[i] = o;
  }
  if (i < hp4) ((float4*)hp)[i] = make_float4(0.f, 0.f, 0.f, 0.f);
  if (i < n) {
    int g = batch[i];
    if (i == 0 || batch[i - 1] != g) root[g] = i;
  }
  if (blockIdx.x < HISTB) {
    h[t] = 0; h[t + 256] = 0;
    __syncthreads();
    int E4 = E >> 2;
    const int4* d4 = (const int4*)dst;
    for (int e = blockIdx.x * 256 + t; e < E4; e += HISTB * 256) {
      int4 d = d4[e];
      atomicAdd(&h[d.x >> BSHIFT], 1);
      atomicAdd(&h[d.y >> BSHIFT], 1);
      atomicAdd(&h[d.z >> BSHIFT], 1);
      atomicAdd(&h[d.w >> BSHIFT], 1);
    }
    if (blockIdx.x == 0)
      for (int e = (E4 << 2) + t; e < E; e += 256)
        atomicAdd(&h[dst[e] >> BSHIFT], 1);
    __syncthreads();
    if (h[t]) atomicAdd(&bcount[t], h[t]);
    if (h[t + 256]) atomicAdd(&bcount[t + 256], h[t + 256]);
  }
}

// ---------------------------------------------------------------------------
// Partition (src<<8 | dst&255) records into bucket regions.
// int4-batched edge loads -> 4-way ILP instead of serial load->atomic chains.
// ---------------------------------------------------------------------------

__global__ __launch_bounds__(256) void k_scatter(
    const int* __restrict__ src, const int* __restrict__ dst,
    const int* __restrict__ bcount, int* __restrict__ cursor0,
    uint32_t* __restrict__ rec, int E) {
  __shared__ int sBB[512];
  __shared__ int stmp[256];
  __shared__ int h[512];
  __shared__ int hb[512];
  __shared__ int lcur[512];
  int t = threadIdx.x;
  int c0 = bcount[2 * t], c1 = bcount[2 * t + 1];
  stmp[t] = c0 + c1;
  h[2 * t] = 0; h[2 * t + 1] = 0;
  lcur[2 * t] = 0; lcur[2 * t + 1] = 0;
  __syncthreads();
  for (int off = 1; off < 256; off <<= 1) {
    int v = (t >= off) ? stmp[t - off] : 0;
    __syncthreads();
    stmp[t] += v;
    __syncthreads();
  }
  int ex = stmp[t] - (c0 + c1);
  sBB[2 * t] = ex;
  sBB[2 * t + 1] = ex + c0;
  __syncthreads();

  int e0 = blockIdx.x * EPB;
  int e1 = e0 + EPB < E ? e0 + EPB : E;
  int cnt = e1 - e0;
  int cnt4 = cnt >> 2;
  const int4* d4 = (const int4*)(dst + e0);
  const int4* s4 = (const int4*)(src + e0);

  for (int i = t; i < cnt4; i += 256) {
    int4 d = d4[i];
    atomicAdd(&h[d.x >> BSHIFT], 1);
    atomicAdd(&h[d.y >> BSHIFT], 1);
    atomicAdd(&h[d.z >> BSHIFT], 1);
    atomicAdd(&h[d.w >> BSHIFT], 1);
  }
  for (int i = (cnt4 << 2) + t; i < cnt; i += 256)
    atomicAdd(&h[dst[e0 + i] >> BSHIFT], 1);
  __syncthreads();
  for (int j = t; j < 512; j += 256)
    if (h[j]) hb[j] = sBB[j] + atomicAdd(&cursor0[j], h[j]);
  __syncthreads();
  for (int i = t; i < cnt4; i += 256) {
    int4 d = d4[i];
    int4 s = s4[i];
    {
      int b = d.x >> BSHIFT; int r = atomicAdd(&lcur[b], 1);
      rec[hb[b] + r] = ((uint32_t)s.x << BSHIFT) | ((uint32_t)d.x & (BNODES - 1));
    }
    {
      int b = d.y >> BSHIFT; int r = atomicAdd(&lcur[b], 1);
      rec[hb[b] + r] = ((uint32_t)s.y << BSHIFT) | ((uint32_t)d.y & (BNODES - 1));
    }
    {
      int b = d.z >> BSHIFT; int r = atomicAdd(&lcur[b], 1);
      rec[hb[b] + r] = ((uint32_t)s.z << BSHIFT) | ((uint32_t)d.z & (BNODES - 1));
    }
    {
      int b = d.w >> BSHIFT; int r = atomicAdd(&lcur[b], 1);
      rec[hb[b] + r] = ((uint32_t)s.w << BSHIFT) | ((uint32_t)d.w & (BNODES - 1));
    }
  }
  for (int i = (cnt4 << 2) + t; i < cnt; i += 256) {
    int d = dst[e0 + i];
    int b = d >> BSHIFT;
    int r = atomicAdd(&lcur[b], 1);
    rec[hb[b] + r] = ((uint32_t)src[e0 + i] << BSHIFT) | ((uint32_t)d & (BNODES - 1));
  }
}

// ---------------------------------------------------------------------------
// Per-bucket CSR, lists padded to multiple of 4 (pads -> zero row),
// uint4-batched rec scans. One block per bucket.
// ---------------------------------------------------------------------------

__global__ __launch_bounds__(256) void k_csr(
    const uint32_t* __restrict__ rec, const int* __restrict__ bcount,
    int* __restrict__ row_start, int* __restrict__ deg,
    int* __restrict__ csr, int n, int zrow) {
  __shared__ int stmp[256];
  __shared__ int lexcl[256];
  __shared__ int ldeg[256];
  __shared__ int lcur[256];
  int t = threadIdx.x, b = blockIdx.x;
  int i2 = 2 * t;
  int v = ((i2 < b) ? bcount[i2] : 0) + ((i2 + 1 < b) ? bcount[i2 + 1] : 0);
  stmp[t] = v;
  ldeg[t] = 0;
  __syncthreads();
  for (int off = 128; off > 0; off >>= 1) {
    if (t < off) stmp[t] += stmp[t + off];
    __syncthreads();
  }
  int ebase = stmp[0];
  int ecnt = bcount[b];
  int padbase = ((ebase + 3) & ~3) + PADB * b;
  int node0 = b << BSHIFT;
  __syncthreads();

  const uint32_t* rb = rec + ebase;
  int ec4 = ecnt >> 2;
  for (int i = t; i < ec4; i += 256) {
    uint4 r = *(const uint4*)(rb + i * 4);
    atomicAdd(&ldeg[r.x & (BNODES - 1)], 1);
    atomicAdd(&ldeg[r.y & (BNODES - 1)], 1);
    atomicAdd(&ldeg[r.z & (BNODES - 1)], 1);
    atomicAdd(&ldeg[r.w & (BNODES - 1)], 1);
  }
  for (int i = (ec4 << 2) + t; i < ecnt; i += 256)
    atomicAdd(&ldeg[rb[i] & (BNODES - 1)], 1);
  __syncthreads();
  int d = ldeg[t];
  int P = (d + 3) & ~3;
  stmp[t] = P;
  __syncthreads();
  for (int off = 1; off < 256; off <<= 1) {
    int vv = (t >= off) ? stmp[t - off] : 0;
    __syncthreads();
    stmp[t] += vv;
    __syncthreads();
  }
  int excl = stmp[t] - P;
  lexcl[t] = excl;
  int rs = padbase + excl;
  int node = node0 + t;
  if (node < n) { row_start[node] = rs; deg[node] = d; }
  lcur[t] = 0;
  __syncthreads();
  for (int i = t; i < ec4; i += 256) {
    uint4 r = *(const uint4*)(rb + i * 4);
    {
      int li = r.x & (BNODES - 1); int k = atomicAdd(&lcur[li], 1);
      csr[padbase + lexcl[li] + k] = (int)(r.x >> BSHIFT);
    }
    {
      int li = r.y & (BNODES - 1); int k = atomicAdd(&lcur[li], 1);
      csr[padbase + lexcl[li] + k] = (int)(r.y >> BSHIFT);
    }
    {
      int li = r.z & (BNODES - 1); int k = atomicAdd(&lcur[li], 1);
      csr[padbase + lexcl[li] + k] = (int)(r.z >> BSHIFT);
    }
    {
      int li = r.w & (BNODES - 1); int k = atomicAdd(&lcur[li], 1);
      csr[padbase + lexcl[li] + k] = (int)(r.w >> BSHIFT);
    }
  }
  for (int i = (ec4 << 2) + t; i < ecnt; i += 256) {
    uint32_t r = rb[i];
    int li = r & (BNODES - 1);
    int k = atomicAdd(&lcur[li], 1);
    csr[padbase + lexcl[li] + k] = (int)(r >> BSHIFT);
  }
  for (int k = d; k < P; ++k) csr[rs + k] = zrow;
}

// ---------------------------------------------------------------------------
// Mean aggregation on fp8 rows: quarter-wave per node (4 nodes/wave),
// lane li owns cols 8li..8li+7 -> no cross-lane reduce; pad-to-4 lists.
// ---------------------------------------------------------------------------

__global__ void k_aggr(const uint32_t* __restrict__ xf8, const int* __restrict__ csr,
                       const int* __restrict__ row_start, const int* __restrict__ deg,
                       ushort* __restrict__ aggr, int n) {
  int wid = threadIdx.x >> 6;
  int lane = threadIdx.x & 63;
  int q = lane >> 4, li = lane & 15;
  int node = blockIdx.x * 16 + wid * 4 + q;
  bool alive = node < n;
  int base = alive ? row_start[node] : 0;
  int d = alive ? deg[node] : 0;
  int P = (d + 3) & ~3;
  const uint2* xp = (const uint2*)xf8 + li;   // row stride = 16 uint2
  f32x2 s[4] = {};
  for (int i = 0; i < P; i += 4) {
    int4 ns = *(const int4*)(csr + base + i);
    uint2 a = xp[(size_t)ns.x * 16];
    uint2 b = xp[(size_t)ns.y * 16];
    uint2 c = xp[(size_t)ns.z * 16];
    uint2 e = xp[(size_t)ns.w * 16];
    acc8f8v(s, a); acc8f8v(s, b); acc8f8v(s, c); acc8f8v(s, e);
  }
  if (alive) {
    float inv = 1.0f / (float)(d > 1 ? d : 1);
    uint4 o;
    o.x = (uint32_t)f2bf(s[0].x * inv) | ((uint32_t)f2bf(s[0].y * inv) << 16);
    o.y = (uint32_t)f2bf(s[1].x * inv) | ((uint32_t)f2bf(s[1].y * inv) << 16);
    o.z = (uint32_t)f2bf(s[2].x * inv) | ((uint32_t)f2bf(s[2].y * inv) << 16);
    o.w = (uint32_t)f2bf(s[3].x * inv) | ((uint32_t)f2bf(s[3].y * inv) << 16);
    ((uint4*)(aggr + (size_t)node * IN_C))[li] = o;
  }
}

// ---------------------------------------------------------------------------
// Fused SAGE GEMM (bf16 MFMA) + relu + per-graph max-pool.
// BARRIER-FREE streaming: each wave reads A fragments (dense 16-row x 64-B
// 2D pattern) and B rows DIRECT from global with register double-buffering.
// No LDS staging, no DMA drain -> latency hidden by wave parallelism.
// ---------------------------------------------------------------------------

__global__ __launch_bounds__(256) void k_gemm_pool(
    const ushort* __restrict__ aggrb, const ushort* __restrict__ xb,
    const ushort* __restrict__ Wcat, const float* __restrict__ bl,
    const int* __restrict__ batch, float* __restrict__ hp, int n) {
  __shared__ float sbl[256];
  __shared__ int sBatch[64];

  int t = threadIdx.x;
  int n0 = blockIdx.x * 64;
  sbl[t] = bl[t];
  if (t < 64) sBatch[t] = (n0 + t < n) ? batch[n0 + t] : -1;
  __syncthreads();

  int lane = t & 63, w = t >> 6;
  int q = lane >> 4, m = lane & 15;

  // A row bases (aggr half and x half), B row bases
  const ushort* arow[4];
  const ushort* xrow[4];
  const ushort* wrow[4];
#pragma unroll
  for (int rt = 0; rt < 4; ++rt) {
    int gn = n0 + rt * 16 + m; gn = gn < n ? gn : n - 1;
    arow[rt] = aggrb + (size_t)gn * IN_C + q * 8;
    xrow[rt] = xb + (size_t)gn * IN_C + q * 8;
  }
#pragma unroll
  for (int ct = 0; ct < 4; ++ct)
    wrow[ct] = Wcat + (size_t)(w * 64 + ct * 16 + m) * (2 * IN_C) + q * 8;

  short8 afn[4], bfn[4];
#pragma unroll
  for (int rt = 0; rt < 4; ++rt) afn[rt] = *(const short8*)arow[rt];
#pragma unroll
  for (int ct = 0; ct < 4; ++ct) bfn[ct] = *(const short8*)wrow[ct];

  f32x4 acc[4][4] = {};
#pragma unroll
  for (int kc = 0; kc < 8; ++kc) {
    short8 af[4], bf[4];
#pragma unroll
    for (int rt = 0; rt < 4; ++rt) af[rt] = afn[rt];
#pragma unroll
    for (int ct = 0; ct < 4; ++ct) bf[ct] = bfn[ct];
    if (kc < 7) {
      int kn = kc + 1;
#pragma unroll
      for (int rt = 0; rt < 4; ++rt)
        afn[rt] = (kn < 4) ? *(const short8*)(arow[rt] + kn * 32)
                           : *(const short8*)(xrow[rt] + (kn - 4) * 32);
#pragma unroll
      for (int ct = 0; ct < 4; ++ct)
        bfn[ct] = *(const short8*)(wrow[ct] + kn * 32);
    }
#pragma unroll
    for (int rt = 0; rt < 4; ++rt)
#pragma unroll
      for (int ct = 0; ct < 4; ++ct)
        acc[rt][ct] = __builtin_amdgcn_mfma_f32_16x16x32_bf16(af[rt], bf[ct], acc[rt][ct], 0, 0, 0);
  }

  // epilogue: bias + relu + per-graph max (<=2 graphs per 64-node window)
  int last = n - 1 - n0; last = last < 63 ? last : 63;
  int gA = sBatch[0];
  int gB = sBatch[last];
#pragma unroll
  for (int ct = 0; ct < 4; ++ct) {
    int col = w * 64 + ct * 16 + m;
    float bias = sbl[col];
    float mA = 0.f, mB = 0.f;
#pragma unroll
    for (int rt = 0; rt < 4; ++rt) {
#pragma unroll
      for (int i = 0; i < 4; ++i) {
        int lr = rt * 16 + q * 4 + i;
        if (n0 + lr < n) {
          float v = fmaxf(acc[rt][ct][i] + bias, 0.f);
          if (sBatch[lr] == gA) mA = fmaxf(mA, v);
          else mB = fmaxf(mB, v);
        }
      }
    }
    mA = fmaxf(mA, __shfl_xor(mA, 16)); mA = fmaxf(mA, __shfl_xor(mA, 32));
    mB = fmaxf(mB, __shfl_xor(mB, 16)); mB = fmaxf(mB, __shfl_xor(mB, 32));
    if (q == 0) {
      atomicMax((int*)&hp[(size_t)gA * HID + col], __float_as_int(mA));
      if (gB != gA) atomicMax((int*)&hp[(size_t)gB * HID + col], __float_as_int(mB));
    }
  }
}

// ---------------------------------------------------------------------------
// Fused tail MLP: 32 graphs per block (16 blocks), bf16 MFMA, W prefetch.
// ---------------------------------------------------------------------------

__global__ __launch_bounds__(256) void k_tail(
    const ushort* __restrict__ xb, const float* __restrict__ hp,
    const int* __restrict__ root,
    const ushort* __restrict__ W0b, const float* __restrict__ b0,
    const ushort* __restrict__ W1b, const float* __restrict__ b1,
    const float* __restrict__ W2, const float* __restrict__ b2,
    float* __restrict__ out, int G) {
  __shared__ ushort sCat[32][264];
  __shared__ int sRoot[32];
  __shared__ float pp[256][2];

  int t = threadIdx.x;
  int g0 = blockIdx.x * 32;
  if (t < 32) sRoot[t] = (g0 + t < G) ? root[g0 + t] : 0;
  __syncthreads();

  int lane = t & 63, w = t >> 6;
  int q = lane >> 4, m = lane & 15;

  const ushort* xrow[2];
#pragma unroll
  for (int rt = 0; rt < 2; ++rt)
    xrow[rt] = xb + (size_t)sRoot[rt * 16 + m] * IN_C;

  {
    f32x4 acc[2][4] = {};
#pragma unroll
    for (int kc = 0; kc < 4; ++kc) {
      short8 af[2], bf[4];
#pragma unroll
      for (int rt = 0; rt < 2; ++rt)
        af[rt] = *(const short8*)(xrow[rt] + kc * 32 + q * 8);
#pragma unroll
      for (int ct = 0; ct < 4; ++ct) {
        int col = w * 64 + ct * 16 + m;
        bf[ct] = *(const short8*)(W0b + (size_t)col * IN_C + kc * 32 + q * 8);
      }
#pragma unroll
      for (int rt = 0; rt < 2; ++rt)
#pragma unroll
        for (int ct = 0; ct < 4; ++ct)
          acc[rt][ct] = __builtin_amdgcn_mfma_f32_16x16x32_bf16(af[rt], bf[ct], acc[rt][ct], 0, 0, 0);
    }
#pragma unroll
    for (int ct = 0; ct < 4; ++ct) {
      int col = w * 64 + ct * 16 + m;
      float bias = b0[col];
#pragma unroll
      for (int rt = 0; rt < 2; ++rt)
#pragma unroll
        for (int i = 0; i < 4; ++i) {
          int row = rt * 16 + q * 4 + i;
          sCat[row][col] = f2bf(fmaxf(acc[rt][ct][i] + bias, 0.f));
        }
    }
  }
  __syncthreads();

  f32x4 acc2[2][4] = {};
  short8 bfn[4];
#pragma unroll
  for (int ct = 0; ct < 4; ++ct)
    bfn[ct] = *(const short8*)(W1b + (size_t)(w * 64 + ct * 16 + m) * (2 * HID) + q * 8);
#pragma unroll
  for (int kc = 0; kc < 8; ++kc) {
    short8 af[2], bf[4];
#pragma unroll
    for (int ct = 0; ct < 4; ++ct) bf[ct] = bfn[ct];
    if (kc < 7) {
#pragma unroll
      for (int ct = 0; ct < 4; ++ct)
        bfn[ct] = *(const short8*)(W1b + (size_t)(w * 64 + ct * 16 + m) * (2 * HID) +
                                   (kc + 1) * 32 + q * 8);
    }
#pragma unroll
    for (int rt = 0; rt < 2; ++rt)
      af[rt] = *(const short8*)&sCat[rt * 16 + m][kc * 32 + q * 8];
#pragma unroll
    for (int rt = 0; rt < 2; ++rt)
#pragma unroll
      for (int ct = 0; ct < 4; ++ct)
        acc2[rt][ct] = __builtin_amdgcn_mfma_f32_16x16x32_bf16(af[rt], bf[ct], acc2[rt][ct], 0, 0, 0);
  }
  __syncthreads();
#pragma unroll
  for (int it = 0; it < 8; ++it) {
    int idx = it * 256 + t;
    int r = idx >> 6, c4 = (idx & 63) * 4;
    if (g0 + r < G) {
      float4 v = *(const float4*)(hp + (size_t)(g0 + r) * HID + c4);
      ushort4 o = {f2bf(v.x), f2bf(v.y), f2bf(v.z), f2bf(v.w)};
      *(ushort4*)&sCat[r][c4] = o;
    }
  }
  __syncthreads();
#pragma unroll
  for (int ct = 0; ct < 4; ++ct)
    bfn[ct] = *(const short8*)(W1b + (size_t)(w * 64 + ct * 16 + m) * (2 * HID) + 8 * 32 + q * 8);
#pragma unroll
  for (int kc = 8; kc < 16; ++kc) {
    short8 af[2], bf[4];
#pragma unroll
    for (int ct = 0; ct < 4; ++ct) bf[ct] = bfn[ct];
    if (kc < 15) {
#pragma unroll
      for (int ct = 0; ct < 4; ++ct)
        bfn[ct] = *(const short8*)(W1b + (size_t)(w * 64 + ct * 16 + m) * (2 * HID) +
                                   (kc + 1) * 32 + q * 8);
    }
#pragma unroll
    for (int rt = 0; rt < 2; ++rt)
      af[rt] = *(const short8*)&sCat[rt * 16 + m][(kc - 8) * 32 + q * 8];
#pragma unroll
    for (int rt = 0; rt < 2; ++rt)
#pragma unroll
      for (int ct = 0; ct < 4; ++ct)
        acc2[rt][ct] = __builtin_amdgcn_mfma_f32_16x16x32_bf16(af[rt], bf[ct], acc2[rt][ct], 0, 0, 0);
  }
  __syncthreads();
#pragma unroll
  for (int ct = 0; ct < 4; ++ct) {
    int col = w * 64 + ct * 16 + m;
    float bias = b1[col];
#pragma unroll
    for (int rt = 0; rt < 2; ++rt)
#pragma unroll
      for (int i = 0; i < 4; ++i) {
        int row = rt * 16 + q * 4 + i;
        sCat[row][col] = f2bf(fmaxf(acc2[rt][ct][i] + bias, 0.f));
      }
  }
  __syncthreads();

  {
    int row = t >> 3, qq = t & 7;
    float p0 = 0.f, p1 = 0.f;
    for (int c = qq * 32; c < qq * 32 + 32; ++c) {
      float hv = bf2f(sCat[row][c]);
      p0 += hv * W2[c];
      p1 += hv * W2[HID + c];
    }
    pp[t][0] = p0; pp[t][1] = p1;
  }
  __syncthreads();
  if (t < 32 && g0 + t < G) {
    float l0 = b2[0], l1 = b2[1];
#pragma unroll
    for (int k = 0; k < 8; ++k) { l0 += pp[t * 8 + k][0]; l1 += pp[t * 8 + k][1]; }
    float mx = fmaxf(l0, l1);
    float ls = logf(expf(l0 - mx) + expf(l1 - mx));
    out[(size_t)(g0 + t) * 2 + 0] = l0 - mx - ls;
    out[(size_t)(g0 + t) * 2 + 1] = l1 - mx - ls;
  }
}

// ---------------------------------------------------------------------------

extern "C" void kernel_launch(void* const* d_in, const int* in_sizes, int n_in,
                              void* d_out, int out_size, void* d_ws, size_t ws_size,
                              hipStream_t stream) {
  const float* x  = (const float*)d_in[0];
  const int* ei   = (const int*)d_in[1];
  const int* batch= (const int*)d_in[2];
  const float* Wl = (const float*)d_in[3];
  const float* bl = (const float*)d_in[4];
  const float* Wr = (const float*)d_in[5];
  const float* W0 = (const float*)d_in[6];
  const float* b0 = (const float*)d_in[7];
  const float* W1 = (const float*)d_in[8];
  const float* b1 = (const float*)d_in[9];
  const float* W2 = (const float*)d_in[10];
  const float* b2 = (const float*)d_in[11];
  float* out = (float*)d_out;

  const int N = in_sizes[0] / IN_C;
  const int E = in_sizes[1] / 2;
  const int G = out_size / OUT_C;
  const int* src = ei;
  const int* dst = ei + E;
  const int NB = (N + BNODES - 1) >> BSHIFT;   // 391

  char* w = (char*)d_ws;
  int* deg       = (int*)w; w += (size_t)N * 4;
  int* row_start = (int*)w; w += (size_t)N * 4;
  int* bcount    = (int*)w; w += 2048;
  int* cursor0   = (int*)w; w += 2048;
  int* root      = (int*)w; w += (size_t)G * 4;
  w = (char*)(((uintptr_t)w + 255) & ~(uintptr_t)255);
  int* csr       = (int*)w; w += (size_t)(E + PADB * NB + 8192) * 4;
  w = (char*)(((uintptr_t)w + 255) & ~(uintptr_t)255);
  ushort* xb     = (ushort*)w; w += (size_t)N * IN_C * 2;
  uint32_t* xf8  = (uint32_t*)w; w += (size_t)(N + 1) * IN_C;   // +1 zero row
  ushort* aggrb  = (ushort*)w; w += (size_t)N * IN_C * 2;
  ushort* Wcat   = (ushort*)w; w += (size_t)HID * (2 * IN_C) * 2;
  ushort* W0b    = (ushort*)w; w += (size_t)HID * IN_C * 2;
  ushort* W1b    = (ushort*)w; w += (size_t)HID * 2 * HID * 2;
  float* hp      = (float*)w; w += (size_t)G * HID * 4;
  uint32_t* rec  = (uint32_t*)aggrb;   // dead before k_aggr writes aggrb

  hipMemsetAsync(bcount, 0, 4096, stream);   // bcount + cursor0

  int n4 = N * IN_C / 4;
  k_prep<<<(n4 + 255) / 256, 256, 0, stream>>>(
      x, xb, xf8, n4, Wl, Wr, Wcat, W0, W0b, W1, W1b, batch, root, N,
      dst, E, bcount, hp, G * HID / 4);
  k_scatter<<<(E + EPB - 1) / EPB, 256, 0, stream>>>(src, dst, bcount, cursor0, rec, E);
  k_csr<<<NB, 256, 0, stream>>>(rec, bcount, row_start, deg, csr, N, N);
  k_aggr<<<(N + 15) / 16, 256, 0, stream>>>(xf8, csr, row_start, deg, aggrb, N);
  k_gemm_pool<<<(N + 63) / 64, 256, 0, stream>>>(aggrb, xb, Wcat, bl, batch, hp, N);
  k_tail<<<(G + 31) / 32, 256, 0, stream>>>(xb, hp, root, W0b, b0, W1b, b1, W2, b2, out, G);
}

// Round 13
// 275.437 us; speedup vs baseline: 1.0300x; 1.0300x over previous
//
#include <hip/hip_runtime.h>
#include <hip/hip_bf16.h>
#include <math.h>
#include <stdint.h>

#define IN_C 128
#define HID  256
#define OUT_C 2

// bucketing for CSR build: 256 nodes per bucket
#define BSHIFT 8
#define BNODES 256
#define EPB 4096        // edges per k_scatter block (divisible by 4)
#define HISTB 784       // blocks of k_prep that do the histogram
#define PADB 768        // max pad slack per bucket (3 * 256)

typedef __attribute__((ext_vector_type(8))) short short8;
typedef __attribute__((ext_vector_type(4))) float f32x4;
typedef __attribute__((ext_vector_type(2))) float f32x2;

#if defined(__has_builtin)
#if __has_builtin(__builtin_amdgcn_cvt_pk_f32_fp8) && __has_builtin(__builtin_amdgcn_cvt_pk_fp8_f32)
#define HAVE_FP8_CVT 1
#endif
#if __has_builtin(__builtin_amdgcn_global_load_lds)
#define HAVE_GLL 1
#endif
#endif

__device__ __forceinline__ ushort f2bf(float f) {
  uint32_t u = __float_as_uint(f);
  uint32_t r = u + 0x7FFF + ((u >> 16) & 1);   // RNE
  return (ushort)(r >> 16);
}
__device__ __forceinline__ float bf2f(ushort b) {
  return __uint_as_float(((uint32_t)b) << 16);
}

#ifndef HAVE_FP8_CVT
__device__ __forceinline__ uint32_t f2fp8_1(float f) {
  uint32_t u = __float_as_uint(f);
  uint32_t s = (u >> 24) & 0x80;
  float a = fabsf(f);
  if (a >= 448.f) return s | 0x7E;
  if (a < 0.015625f) {
    uint32_t m = (uint32_t)(a * 512.f + 0.5f);
    return s | m;
  }
  uint32_t r = u & 0x7fffffff;
  r += 0x7FFFF + ((r >> 20) & 1);
  uint32_t e = (r >> 23) - 127;
  if ((int)e > 8) return s | 0x7E;
  return s | ((e + 7) << 3) | ((r >> 20) & 7);
}
__device__ __forceinline__ float fp8_2f(uint32_t b) {
  uint32_t s = (b & 0x80) << 24;
  uint32_t e = (b >> 3) & 0xF, m = b & 7;
  if (e == 0) { float f = (float)m * 0.001953125f; return s ? -f : f; }
  return __uint_as_float(s | ((e + 120) << 23) | (m << 20));
}
#endif

__device__ __forceinline__ void acc8f8v(f32x2* s, uint2 v) {
#ifdef HAVE_FP8_CVT
  s[0] += __builtin_amdgcn_cvt_pk_f32_fp8(v.x, false);
  s[1] += __builtin_amdgcn_cvt_pk_f32_fp8(v.x, true);
  s[2] += __builtin_amdgcn_cvt_pk_f32_fp8(v.y, false);
  s[3] += __builtin_amdgcn_cvt_pk_f32_fp8(v.y, true);
#else
  s[0].x += fp8_2f(v.x & 0xff);         s[0].y += fp8_2f((v.x >> 8) & 0xff);
  s[1].x += fp8_2f((v.x >> 16) & 0xff); s[1].y += fp8_2f(v.x >> 24);
  s[2].x += fp8_2f(v.y & 0xff);         s[2].y += fp8_2f((v.y >> 8) & 0xff);
  s[3].x += fp8_2f((v.y >> 16) & 0xff); s[3].y += fp8_2f(v.y >> 24);
#endif
}

// ---------------------------------------------------------------------------
// Fused prep: casts, root detection, hp zero, zero-row, bucket histogram.
// ---------------------------------------------------------------------------

__global__ void k_prep(const float* __restrict__ x, ushort* __restrict__ xb,
                       uint32_t* __restrict__ xf8, int n4,
                       const float* __restrict__ Wl, const float* __restrict__ Wr,
                       ushort* __restrict__ Wcat,
                       const float* __restrict__ W0, ushort* __restrict__ W0b,
                       const float* __restrict__ W1, ushort* __restrict__ W1b,
                       const int* __restrict__ batch, int* __restrict__ root, int n,
                       const int* __restrict__ dst, int E, int* __restrict__ bcount,
                       float* __restrict__ hp, int hp4) {
  __shared__ int h[512];
  int t = threadIdx.x;
  int i = blockIdx.x * 256 + t;
  if (i < n4) {
    float4 v = ((const float4*)x)[i];
    ushort4 o = {f2bf(v.x), f2bf(v.y), f2bf(v.z), f2bf(v.w)};
    ((ushort4*)xb)[i] = o;
#ifdef HAVE_FP8_CVT
    int p = __builtin_amdgcn_cvt_pk_fp8_f32(v.x, v.y, 0, false);
    p = __builtin_amdgcn_cvt_pk_fp8_f32(v.z, v.w, p, true);
    xf8[i] = (uint32_t)p;
#else
    xf8[i] = f2fp8_1(v.x) | (f2fp8_1(v.y) << 8) | (f2fp8_1(v.z) << 16) |
             (f2fp8_1(v.w) << 24);
#endif
  }
  if (i < 32) xf8[(size_t)n * 32 + i] = 0;   // zero row (pad target)
  if (i < HID * (2 * IN_C) / 4) {
    int c = i >> 6, c4 = (i & 63) * 4;
    float4 v = (c4 < IN_C) ? *(const float4*)(Wl + (size_t)c * IN_C + c4)
                           : *(const float4*)(Wr + (size_t)c * IN_C + (c4 - IN_C));
    ushort4 o = {f2bf(v.x), f2bf(v.y), f2bf(v.z), f2bf(v.w)};
    *(ushort4*)(Wcat + (size_t)c * (2 * IN_C) + c4) = o;
  }
  if (i < HID * IN_C / 4) {
    float4 v = ((const float4*)W0)[i];
    ushort4 o = {f2bf(v.x), f2bf(v.y), f2bf(v.z), f2bf(v.w)};
    ((ushort4*)W0b)[i] = o;
  }
  if (i < HID * 2 * HID / 4) {
    float4 v = ((const float4*)W1)[i];
    ushort4 o = {f2bf(v.x), f2bf(v.y), f2bf(v.z), f2bf(v.w)};
    ((ushort4*)W1b)[i] = o;
  }
  if (i < hp4) ((float4*)hp)[i] = make_float4(0.f, 0.f, 0.f, 0.f);
  if (i < n) {
    int g = batch[i];
    if (i == 0 || batch[i - 1] != g) root[g] = i;
  }
  if (blockIdx.x < HISTB) {
    h[t] = 0; h[t + 256] = 0;
    __syncthreads();
    int E4 = E >> 2;
    const int4* d4 = (const int4*)dst;
    for (int e = blockIdx.x * 256 + t; e < E4; e += HISTB * 256) {
      int4 d = d4[e];
      atomicAdd(&h[d.x >> BSHIFT], 1);
      atomicAdd(&h[d.y >> BSHIFT], 1);
      atomicAdd(&h[d.z >> BSHIFT], 1);
      atomicAdd(&h[d.w >> BSHIFT], 1);
    }
    if (blockIdx.x == 0)
      for (int e = (E4 << 2) + t; e < E; e += 256)
        atomicAdd(&h[dst[e] >> BSHIFT], 1);
    __syncthreads();
    if (h[t]) atomicAdd(&bcount[t], h[t]);
    if (h[t + 256]) atomicAdd(&bcount[t + 256], h[t + 256]);
  }
}

// ---------------------------------------------------------------------------
// Partition (src<<8 | dst&255) records into bucket regions (int4-batched).
// ---------------------------------------------------------------------------

__global__ __launch_bounds__(256) void k_scatter(
    const int* __restrict__ src, const int* __restrict__ dst,
    const int* __restrict__ bcount, int* __restrict__ cursor0,
    uint32_t* __restrict__ rec, int E) {
  __shared__ int sBB[512];
  __shared__ int stmp[256];
  __shared__ int h[512];
  __shared__ int hb[512];
  __shared__ int lcur[512];
  int t = threadIdx.x;
  int c0 = bcount[2 * t], c1 = bcount[2 * t + 1];
  stmp[t] = c0 + c1;
  h[2 * t] = 0; h[2 * t + 1] = 0;
  lcur[2 * t] = 0; lcur[2 * t + 1] = 0;
  __syncthreads();
  for (int off = 1; off < 256; off <<= 1) {
    int v = (t >= off) ? stmp[t - off] : 0;
    __syncthreads();
    stmp[t] += v;
    __syncthreads();
  }
  int ex = stmp[t] - (c0 + c1);
  sBB[2 * t] = ex;
  sBB[2 * t + 1] = ex + c0;
  __syncthreads();

  int e0 = blockIdx.x * EPB;
  int e1 = e0 + EPB < E ? e0 + EPB : E;
  int cnt = e1 - e0;
  int cnt4 = cnt >> 2;
  const int4* d4 = (const int4*)(dst + e0);
  const int4* s4 = (const int4*)(src + e0);

  for (int i = t; i < cnt4; i += 256) {
    int4 d = d4[i];
    atomicAdd(&h[d.x >> BSHIFT], 1);
    atomicAdd(&h[d.y >> BSHIFT], 1);
    atomicAdd(&h[d.z >> BSHIFT], 1);
    atomicAdd(&h[d.w >> BSHIFT], 1);
  }
  for (int i = (cnt4 << 2) + t; i < cnt; i += 256)
    atomicAdd(&h[dst[e0 + i] >> BSHIFT], 1);
  __syncthreads();
  for (int j = t; j < 512; j += 256)
    if (h[j]) hb[j] = sBB[j] + atomicAdd(&cursor0[j], h[j]);
  __syncthreads();
  for (int i = t; i < cnt4; i += 256) {
    int4 d = d4[i];
    int4 s = s4[i];
    {
      int b = d.x >> BSHIFT; int r = atomicAdd(&lcur[b], 1);
      rec[hb[b] + r] = ((uint32_t)s.x << BSHIFT) | ((uint32_t)d.x & (BNODES - 1));
    }
    {
      int b = d.y >> BSHIFT; int r = atomicAdd(&lcur[b], 1);
      rec[hb[b] + r] = ((uint32_t)s.y << BSHIFT) | ((uint32_t)d.y & (BNODES - 1));
    }
    {
      int b = d.z >> BSHIFT; int r = atomicAdd(&lcur[b], 1);
      rec[hb[b] + r] = ((uint32_t)s.z << BSHIFT) | ((uint32_t)d.z & (BNODES - 1));
    }
    {
      int b = d.w >> BSHIFT; int r = atomicAdd(&lcur[b], 1);
      rec[hb[b] + r] = ((uint32_t)s.w << BSHIFT) | ((uint32_t)d.w & (BNODES - 1));
    }
  }
  for (int i = (cnt4 << 2) + t; i < cnt; i += 256) {
    int d = dst[e0 + i];
    int b = d >> BSHIFT;
    int r = atomicAdd(&lcur[b], 1);
    rec[hb[b] + r] = ((uint32_t)src[e0 + i] << BSHIFT) | ((uint32_t)d & (BNODES - 1));
  }
}

// ---------------------------------------------------------------------------
// Per-bucket CSR, lists padded to multiple of 4, uint4-batched rec scans.
// ---------------------------------------------------------------------------

__global__ __launch_bounds__(256) void k_csr(
    const uint32_t* __restrict__ rec, const int* __restrict__ bcount,
    int* __restrict__ row_start, int* __restrict__ deg,
    int* __restrict__ csr, int n, int zrow) {
  __shared__ int stmp[256];
  __shared__ int lexcl[256];
  __shared__ int ldeg[256];
  __shared__ int lcur[256];
  int t = threadIdx.x, b = blockIdx.x;
  int i2 = 2 * t;
  int v = ((i2 < b) ? bcount[i2] : 0) + ((i2 + 1 < b) ? bcount[i2 + 1] : 0);
  stmp[t] = v;
  ldeg[t] = 0;
  __syncthreads();
  for (int off = 128; off > 0; off >>= 1) {
    if (t < off) stmp[t] += stmp[t + off];
    __syncthreads();
  }
  int ebase = stmp[0];
  int ecnt = bcount[b];
  int padbase = ((ebase + 3) & ~3) + PADB * b;
  int node0 = b << BSHIFT;
  __syncthreads();

  const uint32_t* rb = rec + ebase;
  int ec4 = ecnt >> 2;
  for (int i = t; i < ec4; i += 256) {
    uint4 r = *(const uint4*)(rb + i * 4);
    atomicAdd(&ldeg[r.x & (BNODES - 1)], 1);
    atomicAdd(&ldeg[r.y & (BNODES - 1)], 1);
    atomicAdd(&ldeg[r.z & (BNODES - 1)], 1);
    atomicAdd(&ldeg[r.w & (BNODES - 1)], 1);
  }
  for (int i = (ec4 << 2) + t; i < ecnt; i += 256)
    atomicAdd(&ldeg[rb[i] & (BNODES - 1)], 1);
  __syncthreads();
  int d = ldeg[t];
  int P = (d + 3) & ~3;
  stmp[t] = P;
  __syncthreads();
  for (int off = 1; off < 256; off <<= 1) {
    int vv = (t >= off) ? stmp[t - off] : 0;
    __syncthreads();
    stmp[t] += vv;
    __syncthreads();
  }
  int excl = stmp[t] - P;
  lexcl[t] = excl;
  int rs = padbase + excl;
  int node = node0 + t;
  if (node < n) { row_start[node] = rs; deg[node] = d; }
  lcur[t] = 0;
  __syncthreads();
  for (int i = t; i < ec4; i += 256) {
    uint4 r = *(const uint4*)(rb + i * 4);
    {
      int li = r.x & (BNODES - 1); int k = atomicAdd(&lcur[li], 1);
      csr[padbase + lexcl[li] + k] = (int)(r.x >> BSHIFT);
    }
    {
      int li = r.y & (BNODES - 1); int k = atomicAdd(&lcur[li], 1);
      csr[padbase + lexcl[li] + k] = (int)(r.y >> BSHIFT);
    }
    {
      int li = r.z & (BNODES - 1); int k = atomicAdd(&lcur[li], 1);
      csr[padbase + lexcl[li] + k] = (int)(r.z >> BSHIFT);
    }
    {
      int li = r.w & (BNODES - 1); int k = atomicAdd(&lcur[li], 1);
      csr[padbase + lexcl[li] + k] = (int)(r.w >> BSHIFT);
    }
  }
  for (int i = (ec4 << 2) + t; i < ecnt; i += 256) {
    uint32_t r = rb[i];
    int li = r & (BNODES - 1);
    int k = atomicAdd(&lcur[li], 1);
    csr[padbase + lexcl[li] + k] = (int)(r >> BSHIFT);
  }
  for (int k = d; k < P; ++k) csr[rs + k] = zrow;
}

// ---------------------------------------------------------------------------
// FUSED aggregation + SAGE GEMM + relu + per-graph max-pool.
// Block = 64 nodes x 256 cols.
//  1. DMA xb rows into sX (swizzled; source-side XOR keeps LDS lane-linear).
//  2. Gather-mean 64 nodes from xf8 (quarter-wave/node), write bf16 results
//     straight into sAg (ds_write_b128, phys chunk = li ^ (r&15)).
//  3. One barrier. 4. kc-loop: A frags from LDS, B direct-global w/ prefetch.
// aggrb never exists in memory -> saves 50 MB of HBM round-trip + a launch.
// ---------------------------------------------------------------------------

#ifdef HAVE_GLL
__device__ __forceinline__ void load16_lds(const ushort* g, ushort* l) {
  __builtin_amdgcn_global_load_lds(
      (const __attribute__((address_space(1))) uint32_t*)g,
      (__attribute__((address_space(3))) uint32_t*)l, 16, 0, 0);
}
#endif

__global__ __launch_bounds__(256) void k_fused(
    const uint32_t* __restrict__ xf8, const ushort* __restrict__ xb,
    const int* __restrict__ csr, const int* __restrict__ row_start,
    const int* __restrict__ deg,
    const ushort* __restrict__ Wcat, const float* __restrict__ bl,
    const int* __restrict__ batch, float* __restrict__ hp, int n) {
  __shared__ ushort sAg[64 * 128];   // 16 KB: aggr half (k 0..127)
  __shared__ ushort sX[64 * 128];    // 16 KB: x half   (k 128..255)
  __shared__ float sbl[256];
  __shared__ int sBatch[64];

  int t = threadIdx.x;
  int n0 = blockIdx.x * 64;
  sbl[t] = bl[t];
  if (t < 64) sBatch[t] = (n0 + t < n) ? batch[n0 + t] : -1;

  int lane = t & 63, w = t >> 6;
  int q = lane >> 4, m = lane & 15;
  int li = m;   // quarter-lane index for gather phase

  // ---- 1. DMA x half: 1024 slots (row r, phys p16), 4 instr/thread ----
#pragma unroll
  for (int j = 0; j < 4; ++j) {
    int s = (j * 4 + w) * 64 + lane;
    int r = s >> 4, p16 = s & 15;
    int c16 = p16 ^ (r & 15);
    int gn = n0 + r; gn = gn < n ? gn : n - 1;
    const ushort* g = xb + (size_t)gn * IN_C + c16 * 8;
#ifdef HAVE_GLL
    load16_lds(g, &sX[(size_t)s * 8]);
#else
    *(uint4*)&sX[(size_t)s * 8] = *(const uint4*)g;
#endif
  }

  // ---- 2. gather-mean into sAg: 4 passes x 16 nodes (quarter-wave/node) ----
  const uint2* xp = (const uint2*)xf8 + li;   // row stride = 16 uint2
#pragma unroll
  for (int pass = 0; pass < 4; ++pass) {
    int r = pass * 16 + w * 4 + q;
    int node = n0 + r;
    bool alive = node < n;
    int base = alive ? row_start[node] : 0;
    int d = alive ? deg[node] : 0;
    int P = (d + 3) & ~3;
    f32x2 s[4] = {};
    for (int i = 0; i < P; i += 4) {
      int4 ns = *(const int4*)(csr + base + i);
      uint2 a = xp[(size_t)ns.x * 16];
      uint2 b = xp[(size_t)ns.y * 16];
      uint2 c = xp[(size_t)ns.z * 16];
      uint2 e = xp[(size_t)ns.w * 16];
      acc8f8v(s, a); acc8f8v(s, b); acc8f8v(s, c); acc8f8v(s, e);
    }
    float inv = 1.0f / (float)(d > 1 ? d : 1);
    uint4 o;
    o.x = (uint32_t)f2bf(s[0].x * inv) | ((uint32_t)f2bf(s[0].y * inv) << 16);
    o.y = (uint32_t)f2bf(s[1].x * inv) | ((uint32_t)f2bf(s[1].y * inv) << 16);
    o.z = (uint32_t)f2bf(s[2].x * inv) | ((uint32_t)f2bf(s[2].y * inv) << 16);
    o.w = (uint32_t)f2bf(s[3].x * inv) | ((uint32_t)f2bf(s[3].y * inv) << 16);
    int p = li ^ (r & 15);
    *(uint4*)&sAg[r * 128 + p * 8] = o;
  }

  // ---- 3. B prefetch + barrier ----
  short8 bf_n[4];
#pragma unroll
  for (int ct = 0; ct < 4; ++ct)
    bf_n[ct] = *(const short8*)(Wcat + (size_t)(w * 64 + ct * 16 + m) * (2 * IN_C) + q * 8);

  __syncthreads();   // drains DMA + gather LDS writes

  // ---- 4. kc loop ----
  f32x4 acc[4][4] = {};
#pragma unroll
  for (int kc = 0; kc < 8; ++kc) {
    short8 bf[4];
#pragma unroll
    for (int ct = 0; ct < 4; ++ct) bf[ct] = bf_n[ct];
    if (kc < 7) {
#pragma unroll
      for (int ct = 0; ct < 4; ++ct)
        bf_n[ct] = *(const short8*)(Wcat + (size_t)(w * 64 + ct * 16 + m) * (2 * IN_C) +
                                    (kc + 1) * 32 + q * 8);
    }
    const ushort* half = (kc < 4) ? sAg : sX;
    int lc = ((kc & 3) * 4 + q);
    short8 af[4];
#pragma unroll
    for (int rt = 0; rt < 4; ++rt) {
      int r = rt * 16 + m;
      int p = lc ^ m;
      af[rt] = *(const short8*)&half[r * 128 + p * 8];
    }
#pragma unroll
    for (int rt = 0; rt < 4; ++rt)
#pragma unroll
      for (int ct = 0; ct < 4; ++ct)
        acc[rt][ct] = __builtin_amdgcn_mfma_f32_16x16x32_bf16(af[rt], bf[ct], acc[rt][ct], 0, 0, 0);
  }

  // ---- epilogue: bias + relu + per-graph max ----
  int last = n - 1 - n0; last = last < 63 ? last : 63;
  int gA = sBatch[0];
  int gB = sBatch[last];
#pragma unroll
  for (int ct = 0; ct < 4; ++ct) {
    int col = w * 64 + ct * 16 + m;
    float bias = sbl[col];
    float mA = 0.f, mB = 0.f;
#pragma unroll
    for (int rt = 0; rt < 4; ++rt) {
#pragma unroll
      for (int i = 0; i < 4; ++i) {
        int lr = rt * 16 + q * 4 + i;
        if (n0 + lr < n) {
          float v = fmaxf(acc[rt][ct][i] + bias, 0.f);
          if (sBatch[lr] == gA) mA = fmaxf(mA, v);
          else mB = fmaxf(mB, v);
        }
      }
    }
    mA = fmaxf(mA, __shfl_xor(mA, 16)); mA = fmaxf(mA, __shfl_xor(mA, 32));
    mB = fmaxf(mB, __shfl_xor(mB, 16)); mB = fmaxf(mB, __shfl_xor(mB, 32));
    if (q == 0) {
      atomicMax((int*)&hp[(size_t)gA * HID + col], __float_as_int(mA));
      if (gB != gA) atomicMax((int*)&hp[(size_t)gB * HID + col], __float_as_int(mB));
    }
  }
}

// ---------------------------------------------------------------------------
// Fused tail MLP: 32 graphs per block (16 blocks), bf16 MFMA, W prefetch.
// ---------------------------------------------------------------------------

__global__ __launch_bounds__(256) void k_tail(
    const ushort* __restrict__ xb, const float* __restrict__ hp,
    const int* __restrict__ root,
    const ushort* __restrict__ W0b, const float* __restrict__ b0,
    const ushort* __restrict__ W1b, const float* __restrict__ b1,
    const float* __restrict__ W2, const float* __restrict__ b2,
    float* __restrict__ out, int G) {
  __shared__ ushort sCat[32][264];
  __shared__ int sRoot[32];
  __shared__ float pp[256][2];

  int t = threadIdx.x;
  int g0 = blockIdx.x * 32;
  if (t < 32) sRoot[t] = (g0 + t < G) ? root[g0 + t] : 0;
  __syncthreads();

  int lane = t & 63, w = t >> 6;
  int q = lane >> 4, m = lane & 15;

  const ushort* xrow[2];
#pragma unroll
  for (int rt = 0; rt < 2; ++rt)
    xrow[rt] = xb + (size_t)sRoot[rt * 16 + m] * IN_C;

  {
    f32x4 acc[2][4] = {};
#pragma unroll
    for (int kc = 0; kc < 4; ++kc) {
      short8 af[2], bf[4];
#pragma unroll
      for (int rt = 0; rt < 2; ++rt)
        af[rt] = *(const short8*)(xrow[rt] + kc * 32 + q * 8);
#pragma unroll
      for (int ct = 0; ct < 4; ++ct) {
        int col = w * 64 + ct * 16 + m;
        bf[ct] = *(const short8*)(W0b + (size_t)col * IN_C + kc * 32 + q * 8);
      }
#pragma unroll
      for (int rt = 0; rt < 2; ++rt)
#pragma unroll
        for (int ct = 0; ct < 4; ++ct)
          acc[rt][ct] = __builtin_amdgcn_mfma_f32_16x16x32_bf16(af[rt], bf[ct], acc[rt][ct], 0, 0, 0);
    }
#pragma unroll
    for (int ct = 0; ct < 4; ++ct) {
      int col = w * 64 + ct * 16 + m;
      float bias = b0[col];
#pragma unroll
      for (int rt = 0; rt < 2; ++rt)
#pragma unroll
        for (int i = 0; i < 4; ++i) {
          int row = rt * 16 + q * 4 + i;
          sCat[row][col] = f2bf(fmaxf(acc[rt][ct][i] + bias, 0.f));
        }
    }
  }
  __syncthreads();

  f32x4 acc2[2][4] = {};
  short8 bfn[4];
#pragma unroll
  for (int ct = 0; ct < 4; ++ct)
    bfn[ct] = *(const short8*)(W1b + (size_t)(w * 64 + ct * 16 + m) * (2 * HID) + q * 8);
#pragma unroll
  for (int kc = 0; kc < 8; ++kc) {
    short8 af[2], bf[4];
#pragma unroll
    for (int ct = 0; ct < 4; ++ct) bf[ct] = bfn[ct];
    if (kc < 7) {
#pragma unroll
      for (int ct = 0; ct < 4; ++ct)
        bfn[ct] = *(const short8*)(W1b + (size_t)(w * 64 + ct * 16 + m) * (2 * HID) +
                                   (kc + 1) * 32 + q * 8);
    }
#pragma unroll
    for (int rt = 0; rt < 2; ++rt)
      af[rt] = *(const short8*)&sCat[rt * 16 + m][kc * 32 + q * 8];
#pragma unroll
    for (int rt = 0; rt < 2; ++rt)
#pragma unroll
      for (int ct = 0; ct < 4; ++ct)
        acc2[rt][ct] = __builtin_amdgcn_mfma_f32_16x16x32_bf16(af[rt], bf[ct], acc2[rt][ct], 0, 0, 0);
  }
  __syncthreads();
#pragma unroll
  for (int it = 0; it < 8; ++it) {
    int idx = it * 256 + t;
    int r = idx >> 6, c4 = (idx & 63) * 4;
    if (g0 + r < G) {
      float4 v = *(const float4*)(hp + (size_t)(g0 + r) * HID + c4);
      ushort4 o = {f2bf(v.x), f2bf(v.y), f2bf(v.z), f2bf(v.w)};
      *(ushort4*)&sCat[r][c4] = o;
    }
  }
  __syncthreads();
#pragma unroll
  for (int ct = 0; ct < 4; ++ct)
    bfn[ct] = *(const short8*)(W1b + (size_t)(w * 64 + ct * 16 + m) * (2 * HID) + 8 * 32 + q * 8);
#pragma unroll
  for (int kc = 8; kc < 16; ++kc) {
    short8 af[2], bf[4];
#pragma unroll
    for (int ct = 0; ct < 4; ++ct) bf[ct] = bfn[ct];
    if (kc < 15) {
#pragma unroll
      for (int ct = 0; ct < 4; ++ct)
        bfn[ct] = *(const short8*)(W1b + (size_t)(w * 64 + ct * 16 + m) * (2 * HID) +
                                   (kc + 1) * 32 + q * 8);
    }
#pragma unroll
    for (int rt = 0; rt < 2; ++rt)
      af[rt] = *(const short8*)&sCat[rt * 16 + m][(kc - 8) * 32 + q * 8];
#pragma unroll
    for (int rt = 0; rt < 2; ++rt)
#pragma unroll
      for (int ct = 0; ct < 4; ++ct)
        acc2[rt][ct] = __builtin_amdgcn_mfma_f32_16x16x32_bf16(af[rt], bf[ct], acc2[rt][ct], 0, 0, 0);
  }
  __syncthreads();
#pragma unroll
  for (int ct = 0; ct < 4; ++ct) {
    int col = w * 64 + ct * 16 + m;
    float bias = b1[col];
#pragma unroll
    for (int rt = 0; rt < 2; ++rt)
#pragma unroll
      for (int i = 0; i < 4; ++i) {
        int row = rt * 16 + q * 4 + i;
        sCat[row][col] = f2bf(fmaxf(acc2[rt][ct][i] + bias, 0.f));
      }
  }
  __syncthreads();

  {
    int row = t >> 3, qq = t & 7;
    float p0 = 0.f, p1 = 0.f;
    for (int c = qq * 32; c < qq * 32 + 32; ++c) {
      float hv = bf2f(sCat[row][c]);
      p0 += hv * W2[c];
      p1 += hv * W2[HID + c];
    }
    pp[t][0] = p0; pp[t][1] = p1;
  }
  __syncthreads();
  if (t < 32 && g0 + t < G) {
    float l0 = b2[0], l1 = b2[1];
#pragma unroll
    for (int k = 0; k < 8; ++k) { l0 += pp[t * 8 + k][0]; l1 += pp[t * 8 + k][1]; }
    float mx = fmaxf(l0, l1);
    float ls = logf(expf(l0 - mx) + expf(l1 - mx));
    out[(size_t)(g0 + t) * 2 + 0] = l0 - mx - ls;
    out[(size_t)(g0 + t) * 2 + 1] = l1 - mx - ls;
  }
}

// ---------------------------------------------------------------------------

extern "C" void kernel_launch(void* const* d_in, const int* in_sizes, int n_in,
                              void* d_out, int out_size, void* d_ws, size_t ws_size,
                              hipStream_t stream) {
  const float* x  = (const float*)d_in[0];
  const int* ei   = (const int*)d_in[1];
  const int* batch= (const int*)d_in[2];
  const float* Wl = (const float*)d_in[3];
  const float* bl = (const float*)d_in[4];
  const float* Wr = (const float*)d_in[5];
  const float* W0 = (const float*)d_in[6];
  const float* b0 = (const float*)d_in[7];
  const float* W1 = (const float*)d_in[8];
  const float* b1 = (const float*)d_in[9];
  const float* W2 = (const float*)d_in[10];
  const float* b2 = (const float*)d_in[11];
  float* out = (float*)d_out;

  const int N = in_sizes[0] / IN_C;
  const int E = in_sizes[1] / 2;
  const int G = out_size / OUT_C;
  const int* src = ei;
  const int* dst = ei + E;
  const int NB = (N + BNODES - 1) >> BSHIFT;   // 391

  char* w = (char*)d_ws;
  int* deg       = (int*)w; w += (size_t)N * 4;
  int* row_start = (int*)w; w += (size_t)N * 4;
  int* bcount    = (int*)w; w += 2048;
  int* cursor0   = (int*)w; w += 2048;
  int* root      = (int*)w; w += (size_t)G * 4;
  w = (char*)(((uintptr_t)w + 255) & ~(uintptr_t)255);
  int* csr       = (int*)w; w += (size_t)(E + PADB * NB + 8192) * 4;
  w = (char*)(((uintptr_t)w + 255) & ~(uintptr_t)255);
  uint32_t* rec  = (uint32_t*)w; w += (size_t)E * 4;
  w = (char*)(((uintptr_t)w + 255) & ~(uintptr_t)255);
  ushort* xb     = (ushort*)w; w += (size_t)N * IN_C * 2;
  uint32_t* xf8  = (uint32_t*)w; w += (size_t)(N + 1) * IN_C;   // +1 zero row
  ushort* Wcat   = (ushort*)w; w += (size_t)HID * (2 * IN_C) * 2;
  ushort* W0b    = (ushort*)w; w += (size_t)HID * IN_C * 2;
  ushort* W1b    = (ushort*)w; w += (size_t)HID * 2 * HID * 2;
  float* hp      = (float*)w; w += (size_t)G * HID * 4;

  hipMemsetAsync(bcount, 0, 4096, stream);   // bcount + cursor0

  int n4 = N * IN_C / 4;
  k_prep<<<(n4 + 255) / 256, 256, 0, stream>>>(
      x, xb, xf8, n4, Wl, Wr, Wcat, W0, W0b, W1, W1b, batch, root, N,
      dst, E, bcount, hp, G * HID / 4);
  k_scatter<<<(E + EPB - 1) / EPB, 256, 0, stream>>>(src, dst, bcount, cursor0, rec, E);
  k_csr<<<NB, 256, 0, stream>>>(rec, bcount, row_start, deg, csr, N, N);
  k_fused<<<(N + 63) / 64, 256, 0, stream>>>(xf8, xb, csr, row_start, deg,
                                             Wcat, bl, batch, hp, N);
  k_tail<<<(G + 31) / 32, 256, 0, stream>>>(xb, hp, root, W0b, b0, W1b, b1, W2, b2, out, G);
}